// Round 12
// baseline (48270.615 us; speedup 1.0000x reference)
//
#include <hip/hip_runtime.h>

#define T_STEPS 8192
#define HDIM 1024
#define NL0 64            // layer-0 workgroups (1024 thr, wave owns 1 h0 elem)
#define NL1 128           // layer-1 workgroups (1024 thr, wave-pair owns 1 h1 elem)
#define NWG (NL0 + NL1)   // compute WGs (+1 monitor)
#define PVALVE 400000L
typedef unsigned long long u64;

// ---------- helpers ----------
__device__ __forceinline__ float wred(float v) {
#pragma unroll
    for (int s = 32; s >= 1; s >>= 1) v += __shfl_xor(v, s, 64);
    return v;
}
__device__ __forceinline__ int wred_min(int v) {
#pragma unroll
    for (int s = 32; s >= 1; s >>= 1) v = min(v, __shfl_xor(v, s, 64));
    return v;
}
__device__ __forceinline__ float sigm(float x) { return 1.0f / (1.0f + expf(-x)); }

__device__ __forceinline__ void st_coh_i32(int* p, int v) {
    asm volatile("global_store_dword %0, %1, off sc0 sc1" :: "v"(p), "v"(v) : "memory");
}
__device__ __forceinline__ int ld_coh_i32(const int* p) {
    int v;
    asm volatile("global_load_dword %0, %1, off sc0 sc1\n\ts_waitcnt vmcnt(0)"
                 : "=&v"(v) : "v"(p) : "memory");
    return v;
}
__device__ __forceinline__ void st_pair(u64* p, u64 v) {
    asm volatile("global_store_dwordx2 %0, %1, off sc0 sc1" :: "v"(p), "v"(v) : "memory");
}
__device__ __forceinline__ u64 ld_p8(const u64* p) {
    u64 v;
    asm volatile("global_load_dwordx2 %0, %1, off sc0 sc1\n\ts_waitcnt vmcnt(0)"
                 : "=&v"(v) : "v"(p) : "memory");
    return v;
}
__device__ __forceinline__ void ld2p2(const u64* p0, const u64* p1, u64& a, u64& b) {
    asm volatile(
        "global_load_dwordx2 %0, %2, off sc0 sc1\n\t"
        "global_load_dwordx2 %1, %3, off sc0 sc1\n\t"
        "s_waitcnt vmcnt(0)"
        : "=&v"(a), "=&v"(b) : "v"(p0), "v"(p1) : "memory");
}
// fire-and-forget device-scope atomic add (executes at the coherence point)
__device__ __forceinline__ void at_add(int* p, int v) {
    asm volatile("global_atomic_add %0, %1, off" :: "v"(p), "v"(v) : "memory");
}
// monitor: 3 flag dwords at +0, +256B, +512B
__device__ __forceinline__ void ld3i(const int* p, int& a, int& b, int& c) {
    asm volatile(
        "global_load_dword %0, %3, off sc0 sc1\n\t"
        "global_load_dword %1, %3, off offset:256 sc0 sc1\n\t"
        "global_load_dword %2, %3, off offset:512 sc0 sc1\n\t"
        "s_waitcnt vmcnt(0)"
        : "=&v"(a), "=&v"(b), "=&v"(c) : "v"(p) : "memory");
}
__device__ __forceinline__ u64 pack(float h, int tag) {
    return ((u64)(unsigned)tag << 32) | (u64)__float_as_uint(h);
}
__device__ __forceinline__ float pval(u64 q) { return __uint_as_float((unsigned)q); }
__device__ __forceinline__ unsigned ptag(u64 q) { return (unsigned)(q >> 32); }

// ---------- prologue: U = Wih0*Win, V = Wih0*bin + bih0 + bhh0, B1 = bih1 + bhh1 ----------
__global__ void lstm_prologue(const float* __restrict__ Wih0, const float* __restrict__ Win,
                              const float* __restrict__ bin, const float* __restrict__ bih0,
                              const float* __restrict__ bhh0, const float* __restrict__ bih1,
                              const float* __restrict__ bhh1,
                              float* __restrict__ U, float* __restrict__ V, float* __restrict__ B1) {
    const int wv = threadIdx.x >> 6, lane = threadIdx.x & 63;
    const int r = blockIdx.x * 4 + wv;
    const float* wp = Wih0 + (size_t)r * HDIM;
    float au = 0.f, av = 0.f;
#pragma unroll
    for (int j = 0; j < 16; ++j) {
        float wj = wp[lane + 64 * j];
        au += wj * Win[lane + 64 * j];
        av += wj * bin[lane + 64 * j];
    }
    au = wred(au);
    av = wred(av);
    if (lane == 0) {
        U[r] = au;
        V[r] = av + bih0[r] + bhh0[r];
        B1[r] = bih1[r] + bhh1[r];
    }
}

// ---------- persistent async LSTM: counter readiness + single-shot fetch ----------
// flags[0..191]: WG progress; floor replicas flags[256+r*16] (r<32); abort flags[1024].
// cnt0/cnt1: per-slot arrival counters, 32 groups x 16B per slot (cumulative, memset per launch).
__global__ __launch_bounds__(1024, 1) void lstm_persistent(
    const float* __restrict__ inputs, const float* __restrict__ Whh0,
    const float* __restrict__ Wih1, const float* __restrict__ Whh1,
    const float* __restrict__ Wout, int* flags, int* cnt0, int* cnt1, u64* h0q, u64* h1q,
    const float* __restrict__ U, const float* __restrict__ V, const float* __restrict__ B1,
    float* part) {
    __shared__ float kb[2][2048];
    __shared__ float ibuf[T_STEPS];
    __shared__ float psum[16][4];
    __shared__ float hpub[16];
    __shared__ float bld[32], wolds[8];
    __shared__ float osum[2];
    __shared__ int rdy[2], pubcnt[2], lds_ab;
    const int tid = threadIdx.x;
    const int wv = tid >> 6;
    const int lane = tid & 63;
    const int wg = blockIdx.x;
    int* abp = flags + 1024;
    const int* frep = flags + 256 + (wg & 31) * 16;

    // ================= monitor: floor = min over 192 flags -> 32 replicas =================
    if (wg == NWG) {
        if (tid >= 64) return;
        long it = 0;
        for (;;) {
            int a, b, c;
            ld3i(flags + lane, a, b, c);
            int m = wred_min(min(a, min(b, c)));
            if (lane < 32) st_coh_i32(flags + 256 + lane * 16, m);
            if (m >= T_STEPS) break;
            asm volatile("s_sleep 1");
            if ((++it & 63) == 0) {
                if (ld_coh_i32(abp)) break;
                if (it > PVALVE) { if (lane == 0) st_coh_i32(abp, 1); break; }
            }
        }
        return;
    }

    if (tid == 0) { rdy[0] = -1; rdy[1] = -1; pubcnt[0] = 0; pubcnt[1] = 0; lds_ab = 0; }

    if (wg < NL0) {
        // ---- layer 0: wave wv owns h0 elem e0 = wg*16+wv (4 gate rows, K=1024) ----
        const int e0 = wg * 16 + wv;
        float w0[4][16], uu[4], vv[4];
#pragma unroll
        for (int g = 0; g < 4; ++g) {
            const int row = g * HDIM + e0;
            const float* pw = Whh0 + (size_t)row * HDIM;
#pragma unroll
            for (int k = 0; k < 16; ++k) w0[g][k] = pw[lane + 64 * k];
            uu[g] = U[row];
            vv[g] = V[row];
        }
#pragma unroll
        for (int k = 0; k < 8; ++k) ibuf[tid + 1024 * k] = inputs[tid + 1024 * k];
        __syncthreads();

        float c0 = 0.f;
        for (int p = 0; p < T_STEPS; ++p) {
            const int par = p & 1;
            if (p > 0) {
                const int slot = (p - 1) & 63;
                // (a) readiness: wave0 polls 32 counters; others spin on LDS flag
                if (wv == 0) {
                    const int tgt = 2 * (((p - 1) >> 6) + 1);
                    const int* cp = cnt0 + slot * 128 + lane * 4;
                    bool need = (lane < 32);
                    long it = 0;
                    for (;;) {
                        if (need) need = (ld_coh_i32(cp) < tgt);
                        if (!__ballot(need)) break;
                        if ((++it & 63) == 0) {
                            if (ld_coh_i32(abp) || it > PVALVE) {
                                st_coh_i32(abp, 1); lds_ab = 1; break;
                            }
                        }
                    }
                    if (lane == 0)
                        __hip_atomic_store(&rdy[par], p, __ATOMIC_RELEASE,
                                           __HIP_MEMORY_SCOPE_WORKGROUP);
                } else {
                    long it = 0;
                    while (__hip_atomic_load(&rdy[par], __ATOMIC_ACQUIRE,
                                             __HIP_MEMORY_SCOPE_WORKGROUP) < p) {
                        if (++it > 50000000L) { lds_ab = 1; break; }
                    }
                }
                // (b) single-shot slice fetch (1 RT), tag-verified
                const u64* src = h0q + (size_t)slot * 1024 + wv * 64 + lane;
                u64 q = ld_p8(src);
                long it2 = 0;
                while (ptag(q) != (unsigned)p) {
                    q = ld_p8(src);
                    if ((++it2 & 255) == 0) {
                        if (ld_coh_i32(abp) || it2 > PVALVE) {
                            st_coh_i32(abp, 1); lds_ab = 1; break;
                        }
                    }
                }
                kb[par][wv * 64 + lane] = pval(q);
            } else {
                kb[par][wv * 64 + lane] = 0.f;
            }
            __syncthreads();
            if (lds_ab) break;
            if ((p & 3) == 3 && tid == 0) st_coh_i32(flags + wg, p + 1);
            // (c) compute
            float hv[16];
#pragma unroll
            for (int j = 0; j < 16; ++j) hv[j] = kb[par][lane + 64 * j];
            float acc[4];
#pragma unroll
            for (int g = 0; g < 4; ++g) {
                float s = 0.f;
#pragma unroll
                for (int k = 0; k < 16; ++k) s += w0[g][k] * hv[k];
                acc[g] = s;
            }
#pragma unroll
            for (int g = 0; g < 4; ++g) acc[g] = wred(acc[g]);
            const float st = ibuf[p];
            const float gi = acc[0] + st * uu[0] + vv[0];
            const float gf = acc[1] + st * uu[1] + vv[1];
            const float gg = acc[2] + st * uu[2] + vv[2];
            const float go = acc[3] + st * uu[3] + vv[3];
            const float cn = sigm(gf) * c0 + sigm(gi) * tanhf(gg);
            const float hn = sigm(go) * tanhf(cn);
            c0 = cn;
            if (lane == 0) {
                hpub[wv] = hn;
                __hip_atomic_fetch_add(&pubcnt[par], 1, __ATOMIC_RELEASE,
                                       __HIP_MEMORY_SCOPE_WORKGROUP);
            }
            // (d) consolidated publish by wave 15: 2-line burst + ack + counter
            if (wv == 15) {
                const int tgt16 = 16 * ((p >> 1) + 1);
                long it3 = 0;
                while (__hip_atomic_load(&pubcnt[par], __ATOMIC_ACQUIRE,
                                         __HIP_MEMORY_SCOPE_WORKGROUP) < tgt16) {
                    if (++it3 > 50000000L) { lds_ab = 1; break; }
                }
                if (p >= 48 && (p & 7) == 0 && lane < 16) {   // ring backpressure
                    long itf = 0;
                    for (;;) {
                        if (ld_coh_i32(frep) >= p - 40) break;
                        asm volatile("s_sleep 2");
                        if (ld_coh_i32(abp)) break;
                        if (++itf > PVALVE) { st_coh_i32(abp, 1); break; }
                    }
                }
                if (lane < 16)
                    st_pair(h0q + (size_t)(p & 63) * 1024 + wg * 16 + lane,
                            pack(hpub[lane], p + 1));
                asm volatile("s_waitcnt vmcnt(0)" ::: "memory");
                if (lane == 0) at_add(cnt0 + (p & 63) * 128 + (wg >> 1) * 4, 1);
            }
        }
        __syncthreads();
        if (tid == 0) st_coh_i32(flags + wg, T_STEPS);
    } else {
        // ---- layer 1: wave-pair owns h1 elem (waves 0-7: Wih1; 8-15: Whh1) ----
        const int wgb = wg - NL0;
        const int half = wv >> 3;
        const int ew = wv & 7;
        const int e = wgb * 8 + ew;
        const float* wsrc = half ? Whh1 : Wih1;
        float w1[4][16];
#pragma unroll
        for (int g = 0; g < 4; ++g) {
            const int row = g * HDIM + e;
            const float* pw = wsrc + (size_t)row * HDIM;
#pragma unroll
            for (int k = 0; k < 16; ++k) w1[g][k] = pw[lane + 64 * k];
        }
        if (tid < 32) bld[tid] = B1[(tid & 3) * HDIM + wgb * 8 + (tid >> 2)];
        if (tid < 8) wolds[tid] = Wout[wgb * 8 + tid];
        __syncthreads();

        float cst = 0.f;   // c-state for elem wgb*8+lane, live in wave15 lanes<8
        for (int t = 0; t < T_STEPS; ++t) {
            const int par = t & 1;
            const int sl0 = t & 63, sl1 = (t - 1) & 63;
            // (a) readiness: wave0 polls cnt0[sl0] (lanes<32) and cnt1[sl1] (lanes>=32)
            if (wv == 0) {
                const int tg0 = 2 * ((t >> 6) + 1);
                const int tg1 = 4 * (((t - 1) >> 6) + 1);
                const int* cp = (lane < 32) ? (cnt0 + sl0 * 128 + lane * 4)
                                            : (cnt1 + sl1 * 128 + (lane - 32) * 4);
                const int tg = (lane < 32) ? tg0 : tg1;
                bool need = (lane < 32) || (t > 0);
                long it = 0;
                for (;;) {
                    if (need) need = (ld_coh_i32(cp) < tg);
                    if (!__ballot(need)) break;
                    if ((++it & 63) == 0) {
                        if (ld_coh_i32(abp) || it > PVALVE) {
                            st_coh_i32(abp, 1); lds_ab = 1; break;
                        }
                    }
                }
                if (lane == 0)
                    __hip_atomic_store(&rdy[par], t + 1, __ATOMIC_RELEASE,
                                       __HIP_MEMORY_SCOPE_WORKGROUP);
            } else {
                long it = 0;
                while (__hip_atomic_load(&rdy[par], __ATOMIC_ACQUIRE,
                                         __HIP_MEMORY_SCOPE_WORKGROUP) < t + 1) {
                    if (++it > 50000000L) { lds_ab = 1; break; }
                }
            }
            // (b) slice fetch: wv<8 -> h0[t] pairs; wv>=8 -> h1[t-1] pairs (2 pairs/lane, 1 RT)
            {
                const int ci = (wv & 7) * 128 + lane;
                if (!half) {
                    const u64* s0 = h0q + (size_t)sl0 * 1024 + ci;
                    u64 a, b;
                    ld2p2(s0, s0 + 64, a, b);
                    const unsigned xt = (unsigned)(t + 1);
                    long it2 = 0;
                    while ((ptag(a) ^ xt) | (ptag(b) ^ xt)) {
                        ld2p2(s0, s0 + 64, a, b);
                        if ((++it2 & 255) == 0) {
                            if (ld_coh_i32(abp) || it2 > PVALVE) {
                                st_coh_i32(abp, 1); lds_ab = 1; break;
                            }
                        }
                    }
                    kb[par][ci] = pval(a);
                    kb[par][ci + 64] = pval(b);
                } else if (t > 0) {
                    const u64* s1 = h1q + (size_t)sl1 * 1024 + ci;
                    u64 a, b;
                    ld2p2(s1, s1 + 64, a, b);
                    const unsigned xt = (unsigned)t;
                    long it2 = 0;
                    while ((ptag(a) ^ xt) | (ptag(b) ^ xt)) {
                        ld2p2(s1, s1 + 64, a, b);
                        if ((++it2 & 255) == 0) {
                            if (ld_coh_i32(abp) || it2 > PVALVE) {
                                st_coh_i32(abp, 1); lds_ab = 1; break;
                            }
                        }
                    }
                    kb[par][1024 + ci] = pval(a);
                    kb[par][1024 + ci + 64] = pval(b);
                } else {
                    kb[par][1024 + ci] = 0.f;
                    kb[par][1024 + ci + 64] = 0.f;
                }
            }
            __syncthreads();   // S1
            if (lds_ab) break;
            if (tid == 0) {
                if (t >= 1) part[(size_t)(t - 1) * 128 + wgb] = osum[(t - 1) & 1];
                if ((t & 3) == 3) st_coh_i32(flags + NL0 + wgb, t + 1);
            }
            // (c) MAC halves
            float hv[16];
#pragma unroll
            for (int j = 0; j < 16; ++j) hv[j] = kb[par][half * 1024 + lane + 64 * j];
            float acc[4];
#pragma unroll
            for (int g = 0; g < 4; ++g) {
                float s = 0.f;
#pragma unroll
                for (int k = 0; k < 16; ++k) s += w1[g][k] * hv[k];
                acc[g] = s;
            }
#pragma unroll
            for (int g = 0; g < 4; ++g) acc[g] = wred(acc[g]);
            if (lane == 0) {
                psum[wv][0] = acc[0]; psum[wv][1] = acc[1];
                psum[wv][2] = acc[2]; psum[wv][3] = acc[3];
            }
            __syncthreads();   // S2
            // (d) wave15: gates + publish (1 line) + ack + counter + osum
            if (wv == 15) {
                float hn = 0.f, wos = 0.f;
                if (lane < 8) {
                    const float gi = psum[lane][0] + psum[lane + 8][0] + bld[lane * 4 + 0];
                    const float gf = psum[lane][1] + psum[lane + 8][1] + bld[lane * 4 + 1];
                    const float gg = psum[lane][2] + psum[lane + 8][2] + bld[lane * 4 + 2];
                    const float go = psum[lane][3] + psum[lane + 8][3] + bld[lane * 4 + 3];
                    const float cn = sigm(gf) * cst + sigm(gi) * tanhf(gg);
                    hn = sigm(go) * tanhf(cn);
                    cst = cn;
                }
                if (t >= 48 && (t & 7) == 0 && lane < 8) {   // ring backpressure
                    long itf = 0;
                    for (;;) {
                        if (ld_coh_i32(frep) >= t - 40) break;
                        asm volatile("s_sleep 2");
                        if (ld_coh_i32(abp)) break;
                        if (++itf > PVALVE) { st_coh_i32(abp, 1); break; }
                    }
                }
                if (lane < 8) {
                    st_pair(h1q + (size_t)sl0 * 1024 + wgb * 8 + lane, pack(hn, t + 1));
                    wos = wolds[lane] * hn;
                }
                asm volatile("s_waitcnt vmcnt(0)" ::: "memory");
                if (lane == 0) at_add(cnt1 + sl0 * 128 + (wgb >> 2) * 4, 1);
                wos += __shfl_xor(wos, 1, 64);
                wos += __shfl_xor(wos, 2, 64);
                wos += __shfl_xor(wos, 4, 64);
                if (lane == 0) osum[t & 1] = wos;
            }
        }
        __syncthreads();
        if (tid == 0) {
            part[(size_t)(T_STEPS - 1) * 128 + wgb] = osum[(T_STEPS - 1) & 1];
            st_coh_i32(flags + NL0 + wgb, T_STEPS);
        }
    }
}

// ---------- output projection: out[t] = b_out + sum_wb part[t][wb] ----------
__global__ void lstm_finalize(const float* __restrict__ part, const float* __restrict__ bout,
                              float* __restrict__ out) {
    const int t = blockIdx.x * 256 + threadIdx.x;
    if (t < T_STEPS) {
        const float4* p4 = (const float4*)(part + (size_t)t * 128);
        float s = bout[0];
#pragma unroll
        for (int i = 0; i < 32; ++i) {
            float4 v = p4[i];
            s += v.x + v.y + v.z + v.w;
        }
        out[t] = s;
    }
}

extern "C" void kernel_launch(void* const* d_in, const int* in_sizes, int n_in,
                              void* d_out, int out_size, void* d_ws, size_t ws_size,
                              hipStream_t stream) {
    const float* inputs = (const float*)d_in[0];
    const float* Win  = (const float*)d_in[1];
    const float* bin  = (const float*)d_in[2];
    const float* Wih0 = (const float*)d_in[3];
    const float* Whh0 = (const float*)d_in[4];
    const float* bih0 = (const float*)d_in[5];
    const float* bhh0 = (const float*)d_in[6];
    const float* Wih1 = (const float*)d_in[7];
    const float* Whh1 = (const float*)d_in[8];
    const float* bih1 = (const float*)d_in[9];
    const float* bhh1 = (const float*)d_in[10];
    const float* Wout = (const float*)d_in[11];
    const float* bout = (const float*)d_in[12];

    char* ws = (char*)d_ws;
    int*  flags = (int*)ws;                        // 8 KB: progress, floor reps, abort@1024
    int*  cnt0  = (int*)(ws + 8192);               // 64 slots * 32 grp * 16 B = 32 KB
    int*  cnt1  = (int*)(ws + 40960);              // 32 KB (ends 73728)
    u64*  h0q   = (u64*)(ws + 73728);              // 64*1024*8 = 512 KB
    u64*  h1q   = (u64*)(ws + 598016);             // 512 KB (ends 1122304)
    float* U    = (float*)(ws + 1122304);          // 16 KB
    float* V    = (float*)(ws + 1138688);          // 16 KB
    float* B1   = (float*)(ws + 1155072);          // 16 KB (ends 1171456)
    float* part = (float*)(ws + 1171456);          // 8192*128*4 = 4 MB (ends 5365760)

    if (ws_size < (size_t)5365760) return;

    // Zero flags + counters each launch (replay-safe: counter targets restart).
    // h rings self-validate via tags; replay-stale pairs carry identical values.
    hipMemsetAsync(ws, 0, 73728, stream);

    lstm_prologue<<<1024, 256, 0, stream>>>(Wih0, Win, bin, bih0, bhh0, bih1, bhh1, U, V, B1);
    lstm_persistent<<<NWG + 1, 1024, 0, stream>>>(inputs, Whh0, Wih1, Whh1, Wout,
                                                  flags, cnt0, cnt1, h0q, h1q, U, V, B1, part);
    lstm_finalize<<<(T_STEPS + 255) / 256, 256, 0, stream>>>(part, bout, (float*)d_out);
}

// Round 13
// 46160.754 us; speedup vs baseline: 1.0457x; 1.0457x over previous
//
#include <hip/hip_runtime.h>

#define T_STEPS 8192
#define HDIM 1024
#define NL0 64            // layer-0 workgroups (1024 thr, wave owns 1 h0 elem)
#define NL1 128           // layer-1 workgroups (1024 thr, wave-pair owns 1 h1 elem)
#define NWG (NL0 + NL1)   // compute WGs (+1 monitor)
#define NREP 8            // data replicas (fan-in reduction)
#define RSLOTS 16         // ring slots per replica
#define RMASK 15
#define PVALVE 400000L
typedef unsigned long long u64;

// ---------- helpers ----------
__device__ __forceinline__ float wred(float v) {
#pragma unroll
    for (int s = 32; s >= 1; s >>= 1) v += __shfl_xor(v, s, 64);
    return v;
}
__device__ __forceinline__ int wred_min(int v) {
#pragma unroll
    for (int s = 32; s >= 1; s >>= 1) v = min(v, __shfl_xor(v, s, 64));
    return v;
}
__device__ __forceinline__ float sigm(float x) { return 1.0f / (1.0f + expf(-x)); }

__device__ __forceinline__ void st_coh_i32(int* p, int v) {
    asm volatile("global_store_dword %0, %1, off sc0 sc1" :: "v"(p), "v"(v) : "memory");
}
__device__ __forceinline__ int ld_coh_i32(const int* p) {
    int v;
    asm volatile("global_load_dword %0, %1, off sc0 sc1\n\ts_waitcnt vmcnt(0)"
                 : "=&v"(v) : "v"(p) : "memory");
    return v;
}
__device__ __forceinline__ void st_pair(u64* p, u64 v) {
    asm volatile("global_store_dwordx2 %0, %1, off sc0 sc1" :: "v"(p), "v"(v) : "memory");
}
__device__ __forceinline__ u64 ld_p8(const u64* p) {
    u64 v;
    asm volatile("global_load_dwordx2 %0, %1, off sc0 sc1\n\ts_waitcnt vmcnt(0)"
                 : "=&v"(v) : "v"(p) : "memory");
    return v;
}
// dual-address pair load, ONE waitcnt (single round-trip per poll iteration)
__device__ __forceinline__ void ld2p2(const u64* p0, const u64* p1, u64& a, u64& b) {
    asm volatile(
        "global_load_dwordx2 %0, %2, off sc0 sc1\n\t"
        "global_load_dwordx2 %1, %3, off sc0 sc1\n\t"
        "s_waitcnt vmcnt(0)"
        : "=&v"(a), "=&v"(b) : "v"(p0), "v"(p1) : "memory");
}
// monitor: 3 flag dwords at +0, +256B, +512B
__device__ __forceinline__ void ld3i(const int* p, int& a, int& b, int& c) {
    asm volatile(
        "global_load_dword %0, %3, off sc0 sc1\n\t"
        "global_load_dword %1, %3, off offset:256 sc0 sc1\n\t"
        "global_load_dword %2, %3, off offset:512 sc0 sc1\n\t"
        "s_waitcnt vmcnt(0)"
        : "=&v"(a), "=&v"(b), "=&v"(c) : "v"(p) : "memory");
}
__device__ __forceinline__ u64 pack(float h, int tag) {
    return ((u64)(unsigned)tag << 32) | (u64)__float_as_uint(h);
}
__device__ __forceinline__ float pval(u64 q) { return __uint_as_float((unsigned)q); }
__device__ __forceinline__ unsigned ptag(u64 q) { return (unsigned)(q >> 32); }

// ---------- prologue: U = Wih0*Win, V = Wih0*bin + bih0 + bhh0, B1 = bih1 + bhh1 ----------
__global__ void lstm_prologue(const float* __restrict__ Wih0, const float* __restrict__ Win,
                              const float* __restrict__ bin, const float* __restrict__ bih0,
                              const float* __restrict__ bhh0, const float* __restrict__ bih1,
                              const float* __restrict__ bhh1,
                              float* __restrict__ U, float* __restrict__ V, float* __restrict__ B1) {
    const int wv = threadIdx.x >> 6, lane = threadIdx.x & 63;
    const int r = blockIdx.x * 4 + wv;
    const float* wp = Wih0 + (size_t)r * HDIM;
    float au = 0.f, av = 0.f;
#pragma unroll
    for (int j = 0; j < 16; ++j) {
        float wj = wp[lane + 64 * j];
        au += wj * Win[lane + 64 * j];
        av += wj * bin[lane + 64 * j];
    }
    au = wred(au);
    av = wred(av);
    if (lane == 0) {
        U[r] = au;
        V[r] = av + bih0[r] + bhh0[r];
        B1[r] = bih1[r] + bhh1[r];
    }
}

// ---------- persistent async LSTM: 8x-replicated rings (per-line fan-in cut 8x) ----------
// flags[0..63]=L0 WGs, flags[64..191]=L1 WGs; floor replicas flags[256+r*16] r<32; abort flags[1024].
// Ring layout: ring[rep][slot][1024 pairs]; consumer WG polls replica (wg & 7) only.
__global__ __launch_bounds__(1024, 1) void lstm_persistent(
    const float* __restrict__ inputs, const float* __restrict__ Whh0,
    const float* __restrict__ Wih1, const float* __restrict__ Whh1,
    const float* __restrict__ Wout, int* flags, u64* h0q, u64* h1q,
    const float* __restrict__ U, const float* __restrict__ V, const float* __restrict__ B1,
    float* part) {
    __shared__ float kb0[2][1024];
    __shared__ float kb1[2][1024];
    __shared__ float ibuf[T_STEPS];
    __shared__ float psum[16][4];
    __shared__ float bld[32], wolds[8];
    __shared__ float osum[2];
    __shared__ int lds_ab;
    const int tid = threadIdx.x;
    const int wv = tid >> 6;
    const int lane = tid & 63;
    const int wg = blockIdx.x;
    int* abp = flags + 1024;
    const int* frep = flags + 256 + (wg & 31) * 16;
    const int myrep = wg & 7;

    // ================= monitor: floor = min over 192 flags -> 32 replicas =================
    if (wg == NWG) {
        if (tid >= 64) return;
        long it = 0;
        for (;;) {
            int a, b, c;
            ld3i(flags + lane, a, b, c);
            int m = wred_min(min(a, min(b, c)));
            if (lane < 32) st_coh_i32(flags + 256 + lane * 16, m);
            if (m >= T_STEPS) break;
            asm volatile("s_sleep 1");
            if ((++it & 63) == 0) {
                if (ld_coh_i32(abp)) break;
                if (it > PVALVE) { if (lane == 0) st_coh_i32(abp, 1); break; }
            }
        }
        return;
    }

    if (tid == 0) lds_ab = 0;

    if (wg < NL0) {
        // ---- layer 0: wave wv owns h0 elem e0 (4 gate rows, K=1024, 64 wt floats/thread) ----
        const int e0 = wg * 16 + wv;
        float w0[4][16], uu[4], vv[4];
#pragma unroll
        for (int g = 0; g < 4; ++g) {
            const int row = g * HDIM + e0;
            const float* pw = Whh0 + (size_t)row * HDIM;
#pragma unroll
            for (int k = 0; k < 16; ++k) w0[g][k] = pw[lane + 64 * k];
            uu[g] = U[row];
            vv[g] = V[row];
        }
#pragma unroll
        for (int k = 0; k < 8; ++k) ibuf[tid + 1024 * k] = inputs[tid + 1024 * k];
        __syncthreads();

        float c0 = 0.f;
        for (int p = 0; p < T_STEPS; ++p) {
            const int par = p & 1;
            u64 q = 0;
            if (p > 0) {   // predicated poll of OWN replica: pair tid of h0[p-1] (tag p)
                const u64* src = h0q + ((size_t)myrep * RSLOTS + ((p - 1) & RMASK)) * 1024 + tid;
                const unsigned xt = (unsigned)p;
                bool need = true;
                long it = 0;
                for (;;) {
                    if (!__ballot(need)) break;
                    if (need) { q = ld_p8(src); need = (ptag(q) != xt); }
                    if ((++it & 255) == 0) {
                        if (ld_coh_i32(abp) || it > PVALVE) {
                            st_coh_i32(abp, 1); lds_ab = 1; break;
                        }
                    }
                }
            }
            kb0[par][tid] = pval(q);
            __syncthreads();
            if (lds_ab) break;
            if ((p & 3) == 3 && tid == 0) st_coh_i32(flags + wg, p + 1);
            float hv[16];
#pragma unroll
            for (int j = 0; j < 16; ++j) hv[j] = kb0[par][lane + 64 * j];
            float acc[4];
#pragma unroll
            for (int g = 0; g < 4; ++g) {
                float s = 0.f;
#pragma unroll
                for (int k = 0; k < 16; ++k) s += w0[g][k] * hv[k];
                acc[g] = s;
            }
#pragma unroll
            for (int g = 0; g < 4; ++g) acc[g] = wred(acc[g]);
            const float st = ibuf[p];
            const float gi = acc[0] + st * uu[0] + vv[0];
            const float gf = acc[1] + st * uu[1] + vv[1];
            const float gg = acc[2] + st * uu[2] + vv[2];
            const float go = acc[3] + st * uu[3] + vv[3];
            const float cn = sigm(gf) * c0 + sigm(gi) * tanhf(gg);
            const float hn = sigm(go) * tanhf(cn);
            c0 = cn;
            // ring gate: every 4 steps require floor >= p-8 (overwrite-safe bound p-14)
            if (p >= 16 && (p & 3) == 0 && lane == 0) {
                long itf = 0;
                for (;;) {
                    if (ld_coh_i32(frep) >= p - 8) break;
                    asm volatile("s_sleep 2");
                    if (ld_coh_i32(abp)) break;
                    if (++itf > PVALVE) { st_coh_i32(abp, 1); break; }
                }
            }
            // publish h0[p] to all 8 replicas (fire-and-forget, pipelined)
            if (lane == 0) {
                const u64 pk = pack(hn, p + 1);
                const int slot = p & RMASK;
#pragma unroll
                for (int r = 0; r < NREP; ++r)
                    st_pair(h0q + ((size_t)r * RSLOTS + slot) * 1024 + e0, pk);
            }
        }
        __syncthreads();
        if (tid == 0) st_coh_i32(flags + wg, T_STEPS);
    } else {
        // ---- layer 1: wave-pair owns h1 elem (waves 0-7: Wih1 rows; 8-15: Whh1 rows) ----
        const int wgb = wg - NL0;
        const int half = wv >> 3;
        const int ew = wv & 7;
        const int e = wgb * 8 + ew;
        const float* wsrc = half ? Whh1 : Wih1;
        float w1[4][16];
#pragma unroll
        for (int g = 0; g < 4; ++g) {
            const int row = g * HDIM + e;
            const float* pw = wsrc + (size_t)row * HDIM;
#pragma unroll
            for (int k = 0; k < 16; ++k) w1[g][k] = pw[lane + 64 * k];
        }
        if (tid < 32) bld[tid] = B1[(tid & 3) * HDIM + wgb * 8 + (tid >> 2)];
        if (tid < 8) wolds[tid] = Wout[wgb * 8 + tid];
        __syncthreads();

        float cst = 0.f;
        for (int t = 0; t < T_STEPS; ++t) {
            const int par = t & 1;
            u64 q0 = 0, q1 = 0;
            {   // predicated dual poll of OWN replicas, one waitcnt per iteration
                const u64* s0 = h0q + ((size_t)myrep * RSLOTS + (t & RMASK)) * 1024 + tid;
                const u64* s1 = h1q + ((size_t)myrep * RSLOTS + ((t - 1) & RMASK)) * 1024 + tid;
                const unsigned xt0 = (unsigned)(t + 1), xt1 = (unsigned)t;
                bool n0 = true, n1 = (t > 0);
                long it = 0;
                for (;;) {
                    if (!__ballot(n0 || n1)) break;
                    if (n0 || n1) {
                        u64 a, b;
                        ld2p2(s0, s1, a, b);
                        if (n0 && ptag(a) == xt0) { q0 = a; n0 = false; }
                        if (n1 && ptag(b) == xt1) { q1 = b; n1 = false; }
                    }
                    if ((++it & 255) == 0) {
                        if (ld_coh_i32(abp) || it > PVALVE) {
                            st_coh_i32(abp, 1); lds_ab = 1; break;
                        }
                    }
                }
            }
            kb0[par][tid] = pval(q0);
            kb1[par][tid] = pval(q1);
            __syncthreads();   // S1
            if (lds_ab) break;
            if (tid == 0) {
                if (t >= 1) part[(size_t)(t - 1) * 128 + wgb] = osum[(t - 1) & 1];
                if ((t & 3) == 3) st_coh_i32(flags + NL0 + wgb, t + 1);
            }
            // ring gate on wave 15 (overlaps other waves' MACs; S2 orders before publish)
            if (t >= 16 && (t & 3) == 0 && tid == 960) {
                long itf = 0;
                for (;;) {
                    if (ld_coh_i32(frep) >= t - 8) break;
                    asm volatile("s_sleep 2");
                    if (ld_coh_i32(abp)) break;
                    if (++itf > PVALVE) { st_coh_i32(abp, 1); break; }
                }
            }
            float hv[16];
            const float* kb = half ? kb1[par] : kb0[par];
#pragma unroll
            for (int j = 0; j < 16; ++j) hv[j] = kb[lane + 64 * j];
            float acc[4];
#pragma unroll
            for (int g = 0; g < 4; ++g) {
                float s = 0.f;
#pragma unroll
                for (int k = 0; k < 16; ++k) s += w1[g][k] * hv[k];
                acc[g] = s;
            }
#pragma unroll
            for (int g = 0; g < 4; ++g) acc[g] = wred(acc[g]);
            if (lane == 0) {
                psum[wv][0] = acc[0]; psum[wv][1] = acc[1];
                psum[wv][2] = acc[2]; psum[wv][3] = acc[3];
            }
            __syncthreads();   // S2
            if (wv == 0) {   // combine + gates + publish (8 replicas) for the WG's 8 elems
                float wos = 0.f;
                if (lane < 8) {
                    const float gi = psum[lane][0] + psum[lane + 8][0] + bld[lane * 4 + 0];
                    const float gf = psum[lane][1] + psum[lane + 8][1] + bld[lane * 4 + 1];
                    const float gg = psum[lane][2] + psum[lane + 8][2] + bld[lane * 4 + 2];
                    const float go = psum[lane][3] + psum[lane + 8][3] + bld[lane * 4 + 3];
                    const float cn = sigm(gf) * cst + sigm(gi) * tanhf(gg);
                    const float hn = sigm(go) * tanhf(cn);
                    cst = cn;
                    const u64 pk = pack(hn, t + 1);
                    const int slot = t & RMASK;
#pragma unroll
                    for (int r = 0; r < NREP; ++r)
                        st_pair(h1q + ((size_t)r * RSLOTS + slot) * 1024 + wgb * 8 + lane, pk);
                    wos = wolds[lane] * hn;
                }
                wos += __shfl_xor(wos, 1, 64);
                wos += __shfl_xor(wos, 2, 64);
                wos += __shfl_xor(wos, 4, 64);
                if (lane == 0) osum[t & 1] = wos;
            }
        }
        __syncthreads();
        if (tid == 0) {
            part[(size_t)(T_STEPS - 1) * 128 + wgb] = osum[(T_STEPS - 1) & 1];
            st_coh_i32(flags + NL0 + wgb, T_STEPS);
        }
    }
}

// ---------- output projection: out[t] = b_out + sum_wb part[t][wb] ----------
__global__ void lstm_finalize(const float* __restrict__ part, const float* __restrict__ bout,
                              float* __restrict__ out) {
    const int t = blockIdx.x * 256 + threadIdx.x;
    if (t < T_STEPS) {
        const float4* p4 = (const float4*)(part + (size_t)t * 128);
        float s = bout[0];
#pragma unroll
        for (int i = 0; i < 32; ++i) {
            float4 v = p4[i];
            s += v.x + v.y + v.z + v.w;
        }
        out[t] = s;
    }
}

extern "C" void kernel_launch(void* const* d_in, const int* in_sizes, int n_in,
                              void* d_out, int out_size, void* d_ws, size_t ws_size,
                              hipStream_t stream) {
    const float* inputs = (const float*)d_in[0];
    const float* Win  = (const float*)d_in[1];
    const float* bin  = (const float*)d_in[2];
    const float* Wih0 = (const float*)d_in[3];
    const float* Whh0 = (const float*)d_in[4];
    const float* bih0 = (const float*)d_in[5];
    const float* bhh0 = (const float*)d_in[6];
    const float* Wih1 = (const float*)d_in[7];
    const float* Whh1 = (const float*)d_in[8];
    const float* bih1 = (const float*)d_in[9];
    const float* bhh1 = (const float*)d_in[10];
    const float* Wout = (const float*)d_in[11];
    const float* bout = (const float*)d_in[12];

    char* ws = (char*)d_ws;
    int*  flags = (int*)ws;                        // 8 KB: progress, floor replicas, abort@1024
    u64*  h0q   = (u64*)(ws + 8192);               // 8 rep * 16 slots * 8 KB = 1 MB
    u64*  h1q   = (u64*)(ws + 8192 + 1048576);     // 1 MB (ends 2105344)
    float* U    = (float*)(ws + 2105344);          // 16 KB
    float* V    = (float*)(ws + 2121728);          // 16 KB
    float* B1   = (float*)(ws + 2138112);          // 16 KB (ends 2154496)
    float* part = (float*)(ws + 2154496);          // 8192*128*4 = 4 MB (ends 6348800)

    if (ws_size < (size_t)6348800) return;

    // Rings self-validate via tags (1..8192; 0xAA poison never matches; replay-stale
    // tags carry identical deterministic values). Flags/floor/abort must start at 0.
    hipMemsetAsync(ws, 0, 8192, stream);

    lstm_prologue<<<1024, 256, 0, stream>>>(Wih0, Win, bin, bih0, bhh0, bih1, bhh1, U, V, B1);
    lstm_persistent<<<NWG + 1, 1024, 0, stream>>>(inputs, Whh0, Wih1, Whh1, Wout,
                                                  flags, h0q, h1q, U, V, B1, part);
    lstm_finalize<<<(T_STEPS + 255) / 256, 256, 0, stream>>>(part, bout, (float*)d_out);
}

// Round 14
// 36959.839 us; speedup vs baseline: 1.3060x; 1.2489x over previous
//
#include <hip/hip_runtime.h>

#define T_STEPS 8192
#define HDIM 1024
#define NL0 64            // layer-0 workgroups (1024 thr, wave owns 1 h0 elem)
#define NL1 128           // layer-1 workgroups (1024 thr, wave-pair owns 1 h1 elem)
#define NWG (NL0 + NL1)   // compute WGs (+1 monitor)
#define RMASK 63          // ring depth 64
#define PVALVE 400000L
typedef unsigned long long u64;

// ---------- helpers ----------
__device__ __forceinline__ float wred(float v) {
#pragma unroll
    for (int s = 32; s >= 1; s >>= 1) v += __shfl_xor(v, s, 64);
    return v;
}
__device__ __forceinline__ int wred_min(int v) {
#pragma unroll
    for (int s = 32; s >= 1; s >>= 1) v = min(v, __shfl_xor(v, s, 64));
    return v;
}
__device__ __forceinline__ float sigm(float x) { return 1.0f / (1.0f + expf(-x)); }

__device__ __forceinline__ void st_coh_i32(int* p, int v) {
    asm volatile("global_store_dword %0, %1, off sc0 sc1" :: "v"(p), "v"(v) : "memory");
}
__device__ __forceinline__ int ld_coh_i32(const int* p) {
    int v;
    asm volatile("global_load_dword %0, %1, off sc0 sc1\n\ts_waitcnt vmcnt(0)"
                 : "=&v"(v) : "v"(p) : "memory");
    return v;
}
__device__ __forceinline__ void st_pair(u64* p, u64 v) {
    asm volatile("global_store_dwordx2 %0, %1, off sc0 sc1" :: "v"(p), "v"(v) : "memory");
}
__device__ __forceinline__ u64 ld_p8(const u64* p) {
    u64 v;
    asm volatile("global_load_dwordx2 %0, %1, off sc0 sc1\n\ts_waitcnt vmcnt(0)"
                 : "=&v"(v) : "v"(p) : "memory");
    return v;
}
// monitor: 3 flag dwords at +0, +256B, +512B
__device__ __forceinline__ void ld3i(const int* p, int& a, int& b, int& c) {
    asm volatile(
        "global_load_dword %0, %3, off sc0 sc1\n\t"
        "global_load_dword %1, %3, off offset:256 sc0 sc1\n\t"
        "global_load_dword %2, %3, off offset:512 sc0 sc1\n\t"
        "s_waitcnt vmcnt(0)"
        : "=&v"(a), "=&v"(b), "=&v"(c) : "v"(p) : "memory");
}
__device__ __forceinline__ u64 pack(float h, int tag) {
    return ((u64)(unsigned)tag << 32) | (u64)__float_as_uint(h);
}
__device__ __forceinline__ float pval(u64 q) { return __uint_as_float((unsigned)q); }
__device__ __forceinline__ unsigned ptag(u64 q) { return (unsigned)(q >> 32); }

// ---------- prologue: U = Wih0*Win, V = Wih0*bin + bih0 + bhh0, B1 = bih1 + bhh1 ----------
__global__ void lstm_prologue(const float* __restrict__ Wih0, const float* __restrict__ Win,
                              const float* __restrict__ bin, const float* __restrict__ bih0,
                              const float* __restrict__ bhh0, const float* __restrict__ bih1,
                              const float* __restrict__ bhh1,
                              float* __restrict__ U, float* __restrict__ V, float* __restrict__ B1) {
    const int wv = threadIdx.x >> 6, lane = threadIdx.x & 63;
    const int r = blockIdx.x * 4 + wv;
    const float* wp = Wih0 + (size_t)r * HDIM;
    float au = 0.f, av = 0.f;
#pragma unroll
    for (int j = 0; j < 16; ++j) {
        float wj = wp[lane + 64 * j];
        au += wj * Win[lane + 64 * j];
        av += wj * bin[lane + 64 * j];
    }
    au = wred(au);
    av = wred(av);
    if (lane == 0) {
        U[r] = au;
        V[r] = av + bih0[r] + bhh0[r];
        B1[r] = bih1[r] + bhh1[r];
    }
}

// ---------- persistent async LSTM ----------
// __launch_bounds__(1024, 4): a 1024-thr block IS 4 waves/SIMD; declaring 4 sets the
// register cap to 512/4 = 128 VGPRs -> the 64 weight floats stay register-resident
// (previous rounds: compiler targeted 8 waves/SIMD (~60-104 regs) and silently spilled
// the weight arrays, re-reading them from scratch/L2 every step on the MAC path).
// flags[0..63]=L0 WGs, flags[64..191]=L1 WGs; floor replicas flags[256+r*16] r<32; abort flags[1024].
__global__ __launch_bounds__(1024, 4) void lstm_persistent(
    const float* __restrict__ inputs, const float* __restrict__ Whh0,
    const float* __restrict__ Wih1, const float* __restrict__ Whh1,
    const float* __restrict__ Wout, int* flags, u64* h0q, u64* h1q,
    const float* __restrict__ U, const float* __restrict__ V, const float* __restrict__ B1,
    float* part) {
    __shared__ float kb0[2][1024];
    __shared__ float kb1[2][1024];
    __shared__ float ibuf[T_STEPS];
    __shared__ float psum[16][4];
    __shared__ float bld[32], wolds[8];
    __shared__ float osum[2];
    __shared__ int lds_ab;
    const int tid = threadIdx.x;
    const int wv = tid >> 6;
    const int lane = tid & 63;
    const int wg = blockIdx.x;
    int* abp = flags + 1024;
    const int* frep = flags + 256 + (wg & 31) * 16;

    // ================= monitor: floor = min over 192 flags -> 32 replicas =================
    if (wg == NWG) {
        if (tid >= 64) return;
        long it = 0;
        for (;;) {
            int a, b, c;
            ld3i(flags + lane, a, b, c);
            int m = wred_min(min(a, min(b, c)));
            if (lane < 32) st_coh_i32(flags + 256 + lane * 16, m);
            if (m >= T_STEPS) break;
            asm volatile("s_sleep 1");
            if ((++it & 63) == 0) {
                if (ld_coh_i32(abp)) break;
                if (it > PVALVE) { if (lane == 0) st_coh_i32(abp, 1); break; }
            }
        }
        return;
    }

    if (tid == 0) lds_ab = 0;

    if (wg < NL0) {
        // ---- layer 0: wave wv owns h0 elem e0 (4 gate rows, K=1024, 64 wt floats/thread) ----
        const int e0 = wg * 16 + wv;
        float w0[4][16], uu[4], vv[4];
#pragma unroll
        for (int g = 0; g < 4; ++g) {
            const int row = g * HDIM + e0;
            const float* pw = Whh0 + (size_t)row * HDIM;
#pragma unroll
            for (int k = 0; k < 16; ++k) w0[g][k] = pw[lane + 64 * k];
            uu[g] = U[row];
            vv[g] = V[row];
        }
#pragma unroll
        for (int k = 0; k < 8; ++k) ibuf[tid + 1024 * k] = inputs[tid + 1024 * k];
        __syncthreads();

        float c0 = 0.f;
        for (int p = 0; p < T_STEPS; ++p) {
            const int par = p & 1;
            u64 q = 0;
            if (p > 0) {   // predicated poll: thread owns pair tid of h0[p-1] (tag p)
                const u64* src = h0q + (size_t)((p - 1) & RMASK) * 1024 + tid;
                const unsigned xt = (unsigned)p;
                bool need = true;
                long it = 0;
                for (;;) {
                    if (!__ballot(need)) break;
                    if (need) { q = ld_p8(src); need = (ptag(q) != xt); }
                    if ((++it & 255) == 0) {
                        if (ld_coh_i32(abp) || it > PVALVE) {
                            st_coh_i32(abp, 1); lds_ab = 1; break;
                        }
                    }
                }
            }
            kb0[par][tid] = pval(q);
            __syncthreads();
            if (lds_ab) break;
            if ((p & 3) == 3 && tid == 0) st_coh_i32(flags + wg, p + 1);
            float hv[16];
#pragma unroll
            for (int j = 0; j < 16; ++j) hv[j] = kb0[par][lane + 64 * j];
            float acc[4];
#pragma unroll
            for (int g = 0; g < 4; ++g) {
                float s = 0.f;
#pragma unroll
                for (int k = 0; k < 16; ++k) s += w0[g][k] * hv[k];
                acc[g] = s;
            }
#pragma unroll
            for (int g = 0; g < 4; ++g) acc[g] = wred(acc[g]);
            const float st = ibuf[p];
            const float gi = acc[0] + st * uu[0] + vv[0];
            const float gf = acc[1] + st * uu[1] + vv[1];
            const float gg = acc[2] + st * uu[2] + vv[2];
            const float go = acc[3] + st * uu[3] + vv[3];
            const float cn = sigm(gf) * c0 + sigm(gi) * tanhf(gg);
            const float hn = sigm(go) * tanhf(cn);
            c0 = cn;
            if (p >= 48 && (p & 7) == 0 && lane == 0) {   // publisher-lane ring gate
                long itf = 0;
                for (;;) {
                    if (ld_coh_i32(frep) >= p - 40) break;
                    asm volatile("s_sleep 2");
                    if (ld_coh_i32(abp)) break;
                    if (++itf > PVALVE) { st_coh_i32(abp, 1); break; }
                }
            }
            if (lane == 0)
                st_pair(h0q + (size_t)(p & RMASK) * 1024 + e0, pack(hn, p + 1));
        }
        __syncthreads();
        if (tid == 0) st_coh_i32(flags + wg, T_STEPS);
    } else {
        // ---- layer 1: wave-pair owns h1 elem (waves 0-7: Wih1 rows; 8-15: Whh1 rows) ----
        const int wgb = wg - NL0;
        const int half = wv >> 3;
        const int ew = wv & 7;
        const int e = wgb * 8 + ew;
        const float* wsrc = half ? Whh1 : Wih1;
        float w1[4][16];
#pragma unroll
        for (int g = 0; g < 4; ++g) {
            const int row = g * HDIM + e;
            const float* pw = wsrc + (size_t)row * HDIM;
#pragma unroll
            for (int k = 0; k < 16; ++k) w1[g][k] = pw[lane + 64 * k];
        }
        if (tid < 32) bld[tid] = B1[(tid & 3) * HDIM + wgb * 8 + (tid >> 2)];
        if (tid < 8) wolds[tid] = Wout[wgb * 8 + tid];
        __syncthreads();

        float cst = 0.f;
        for (int t = 0; t < T_STEPS; ++t) {
            const int par = t & 1;
            u64 q0 = 0, q1 = 0;
            {   // predicated dual poll: h0[t] (tag t+1) + h1[t-1] (tag t), pair tid each
                const u64* s0 = h0q + (size_t)(t & RMASK) * 1024 + tid;
                const u64* s1 = h1q + (size_t)((t - 1) & RMASK) * 1024 + tid;
                const unsigned xt0 = (unsigned)(t + 1), xt1 = (unsigned)t;
                bool n0 = true, n1 = (t > 0);
                long it = 0;
                for (;;) {
                    if (!__ballot(n0 | n1)) break;
                    if (n0) { q0 = ld_p8(s0); n0 = (ptag(q0) != xt0); }
                    if (n1) { q1 = ld_p8(s1); n1 = (ptag(q1) != xt1); }
                    if ((++it & 255) == 0) {
                        if (ld_coh_i32(abp) || it > PVALVE) {
                            st_coh_i32(abp, 1); lds_ab = 1; break;
                        }
                    }
                }
            }
            kb0[par][tid] = pval(q0);
            kb1[par][tid] = pval(q1);
            __syncthreads();   // S1
            if (lds_ab) break;
            if (tid == 0) {
                if (t >= 1) part[(size_t)(t - 1) * 128 + wgb] = osum[(t - 1) & 1];
                if ((t & 3) == 3) st_coh_i32(flags + NL0 + wgb, t + 1);
            }
            float hv[16];
            const float* kb = half ? kb1[par] : kb0[par];
#pragma unroll
            for (int j = 0; j < 16; ++j) hv[j] = kb[lane + 64 * j];
            float acc[4];
#pragma unroll
            for (int g = 0; g < 4; ++g) {
                float s = 0.f;
#pragma unroll
                for (int k = 0; k < 16; ++k) s += w1[g][k] * hv[k];
                acc[g] = s;
            }
#pragma unroll
            for (int g = 0; g < 4; ++g) acc[g] = wred(acc[g]);
            if (lane == 0) {
                psum[wv][0] = acc[0]; psum[wv][1] = acc[1];
                psum[wv][2] = acc[2]; psum[wv][3] = acc[3];
            }
            __syncthreads();   // S2
            if (t >= 48 && (t & 7) == 0 && tid == 960) {   // ring gate on wave 15
                long itf = 0;
                for (;;) {
                    if (ld_coh_i32(frep) >= t - 40) break;
                    asm volatile("s_sleep 2");
                    if (ld_coh_i32(abp)) break;
                    if (++itf > PVALVE) { st_coh_i32(abp, 1); break; }
                }
            }
            if (wv == 0) {   // combine + gates + publish for the WG's 8 h1 elems
                float wos = 0.f;
                if (lane < 8) {
                    const float gi = psum[lane][0] + psum[lane + 8][0] + bld[lane * 4 + 0];
                    const float gf = psum[lane][1] + psum[lane + 8][1] + bld[lane * 4 + 1];
                    const float gg = psum[lane][2] + psum[lane + 8][2] + bld[lane * 4 + 2];
                    const float go = psum[lane][3] + psum[lane + 8][3] + bld[lane * 4 + 3];
                    const float cn = sigm(gf) * cst + sigm(gi) * tanhf(gg);
                    const float hn = sigm(go) * tanhf(cn);
                    cst = cn;
                    st_pair(h1q + (size_t)(t & RMASK) * 1024 + wgb * 8 + lane, pack(hn, t + 1));
                    wos = wolds[lane] * hn;
                }
                wos += __shfl_xor(wos, 1, 64);
                wos += __shfl_xor(wos, 2, 64);
                wos += __shfl_xor(wos, 4, 64);
                if (lane == 0) osum[t & 1] = wos;
            }
        }
        __syncthreads();
        if (tid == 0) {
            part[(size_t)(T_STEPS - 1) * 128 + wgb] = osum[(T_STEPS - 1) & 1];
            st_coh_i32(flags + NL0 + wgb, T_STEPS);
        }
    }
}

// ---------- output projection: out[t] = b_out + sum_wb part[t][wb] ----------
__global__ void lstm_finalize(const float* __restrict__ part, const float* __restrict__ bout,
                              float* __restrict__ out) {
    const int t = blockIdx.x * 256 + threadIdx.x;
    if (t < T_STEPS) {
        const float4* p4 = (const float4*)(part + (size_t)t * 128);
        float s = bout[0];
#pragma unroll
        for (int i = 0; i < 32; ++i) {
            float4 v = p4[i];
            s += v.x + v.y + v.z + v.w;
        }
        out[t] = s;
    }
}

extern "C" void kernel_launch(void* const* d_in, const int* in_sizes, int n_in,
                              void* d_out, int out_size, void* d_ws, size_t ws_size,
                              hipStream_t stream) {
    const float* inputs = (const float*)d_in[0];
    const float* Win  = (const float*)d_in[1];
    const float* bin  = (const float*)d_in[2];
    const float* Wih0 = (const float*)d_in[3];
    const float* Whh0 = (const float*)d_in[4];
    const float* bih0 = (const float*)d_in[5];
    const float* bhh0 = (const float*)d_in[6];
    const float* Wih1 = (const float*)d_in[7];
    const float* Whh1 = (const float*)d_in[8];
    const float* bih1 = (const float*)d_in[9];
    const float* bhh1 = (const float*)d_in[10];
    const float* Wout = (const float*)d_in[11];
    const float* bout = (const float*)d_in[12];

    char* ws = (char*)d_ws;
    int*  flags = (int*)ws;                        // 8 KB: progress, floor replicas, abort@1024
    u64*  h0q   = (u64*)(ws + 8192);               // 64*1024*8 = 512 KB
    u64*  h1q   = (u64*)(ws + 8192 + 524288);      // 512 KB (ends 1056768)
    float* U    = (float*)(ws + 1056768);          // 16 KB
    float* V    = (float*)(ws + 1073152);          // 16 KB
    float* B1   = (float*)(ws + 1089536);          // 16 KB (ends 1105920)
    float* part = (float*)(ws + 1105920);          // 8192*128*4 = 4 MB (ends 5300224)

    if (ws_size < (size_t)5300224) return;

    // Rings self-validate via tags (1..8192; 0xAA poison never matches; replay-stale
    // tags carry identical deterministic values). Flags/floor/abort must start at 0.
    hipMemsetAsync(ws, 0, 8192, stream);

    lstm_prologue<<<1024, 256, 0, stream>>>(Wih0, Win, bin, bih0, bhh0, bih1, bhh1, U, V, B1);
    lstm_persistent<<<NWG + 1, 1024, 0, stream>>>(inputs, Whh0, Wih1, Whh1, Wout,
                                                  flags, h0q, h1q, U, V, B1, part);
    lstm_finalize<<<(T_STEPS + 255) / 256, 256, 0, stream>>>(part, bout, (float*)d_out);
}

// Round 15
// 36956.201 us; speedup vs baseline: 1.3062x; 1.0001x over previous
//
#include <hip/hip_runtime.h>

#define T_STEPS 8192
#define HDIM 1024
#define NL0 64            // layer-0 workgroups (1024 thr, wave owns 1 h0 elem)
#define NL1 128           // layer-1 workgroups (1024 thr, wave-pair owns 1 h1 elem)
#define NWG (NL0 + NL1)   // compute WGs (+1 monitor)
#define RMASK 63          // ring depth 64
#define PVALVE 400000L
typedef unsigned long long u64;

// ---------- helpers ----------
__device__ __forceinline__ float wred(float v) {
#pragma unroll
    for (int s = 32; s >= 1; s >>= 1) v += __shfl_xor(v, s, 64);
    return v;
}
__device__ __forceinline__ int wred_min(int v) {
#pragma unroll
    for (int s = 32; s >= 1; s >>= 1) v = min(v, __shfl_xor(v, s, 64));
    return v;
}
__device__ __forceinline__ float sigm(float x) { return 1.0f / (1.0f + expf(-x)); }

__device__ __forceinline__ void st_coh_i32(int* p, int v) {
    asm volatile("global_store_dword %0, %1, off sc0 sc1" :: "v"(p), "v"(v) : "memory");
}
__device__ __forceinline__ int ld_coh_i32(const int* p) {
    int v;
    asm volatile("global_load_dword %0, %1, off sc0 sc1\n\ts_waitcnt vmcnt(0)"
                 : "=&v"(v) : "v"(p) : "memory");
    return v;
}
__device__ __forceinline__ void st_pair(u64* p, u64 v) {
    asm volatile("global_store_dwordx2 %0, %1, off sc0 sc1" :: "v"(p), "v"(v) : "memory");
}
__device__ __forceinline__ u64 ld_p8(const u64* p) {
    u64 v;
    asm volatile("global_load_dwordx2 %0, %1, off sc0 sc1\n\ts_waitcnt vmcnt(0)"
                 : "=&v"(v) : "v"(p) : "memory");
    return v;
}
// asm-opaque weight load: result cannot be rematerialized -> stays in a VGPR
__device__ __forceinline__ float ld_wreg(const float* p) {
    float v;
    asm volatile("global_load_dword %0, %1, off\n\ts_waitcnt vmcnt(0)"
                 : "=v"(v) : "v"(p));
    return v;
}
// monitor: 3 flag dwords at +0, +256B, +512B
__device__ __forceinline__ void ld3i(const int* p, int& a, int& b, int& c) {
    asm volatile(
        "global_load_dword %0, %3, off sc0 sc1\n\t"
        "global_load_dword %1, %3, off offset:256 sc0 sc1\n\t"
        "global_load_dword %2, %3, off offset:512 sc0 sc1\n\t"
        "s_waitcnt vmcnt(0)"
        : "=&v"(a), "=&v"(b), "=&v"(c) : "v"(p) : "memory");
}
__device__ __forceinline__ u64 pack(float h, int tag) {
    return ((u64)(unsigned)tag << 32) | (u64)__float_as_uint(h);
}
__device__ __forceinline__ float pval(u64 q) { return __uint_as_float((unsigned)q); }
__device__ __forceinline__ unsigned ptag(u64 q) { return (unsigned)(q >> 32); }

// ---------- prologue: U = Wih0*Win, V = Wih0*bin + bih0 + bhh0, B1 = bih1 + bhh1 ----------
__global__ void lstm_prologue(const float* __restrict__ Wih0, const float* __restrict__ Win,
                              const float* __restrict__ bin, const float* __restrict__ bih0,
                              const float* __restrict__ bhh0, const float* __restrict__ bih1,
                              const float* __restrict__ bhh1,
                              float* __restrict__ U, float* __restrict__ V, float* __restrict__ B1) {
    const int wv = threadIdx.x >> 6, lane = threadIdx.x & 63;
    const int r = blockIdx.x * 4 + wv;
    const float* wp = Wih0 + (size_t)r * HDIM;
    float au = 0.f, av = 0.f;
#pragma unroll
    for (int j = 0; j < 16; ++j) {
        float wj = wp[lane + 64 * j];
        au += wj * Win[lane + 64 * j];
        av += wj * bin[lane + 64 * j];
    }
    au = wred(au);
    av = wred(av);
    if (lane == 0) {
        U[r] = au;
        V[r] = av + bih0[r] + bhh0[r];
        B1[r] = bih1[r] + bhh1[r];
    }
}

// ---------- persistent async LSTM: asm-pinned register-resident weights ----------
// __launch_bounds__(1024, 4) -> 128-VGPR budget; ld_wreg results cannot be
// rematerialized, so the 64 weight floats/thread live in VGPRs across all 8192
// steps (previous rounds: compiler sank weight loads into the loop, re-reading
// 256KB/WG from L2 every step on the MAC critical path ~1.5us/step).
// flags[0..63]=L0 WGs, flags[64..191]=L1 WGs; floor replicas flags[256+r*16] r<32; abort flags[1024].
__global__ __launch_bounds__(1024, 4) void lstm_persistent(
    const float* __restrict__ inputs, const float* __restrict__ Whh0,
    const float* __restrict__ Wih1, const float* __restrict__ Whh1,
    const float* __restrict__ Wout, int* flags, u64* h0q, u64* h1q,
    const float* __restrict__ U, const float* __restrict__ V, const float* __restrict__ B1,
    float* part) {
    __shared__ float kb0[2][1024];
    __shared__ float kb1[2][1024];
    __shared__ float ibuf[T_STEPS];
    __shared__ float psum[16][4];
    __shared__ float bld[32], wolds[8];
    __shared__ float osum[2];
    __shared__ int lds_ab;
    const int tid = threadIdx.x;
    const int wv = tid >> 6;
    const int lane = tid & 63;
    const int wg = blockIdx.x;
    int* abp = flags + 1024;
    const int* frep = flags + 256 + (wg & 31) * 16;

    // ================= monitor: floor = min over 192 flags -> 32 replicas =================
    if (wg == NWG) {
        if (tid >= 64) return;
        long it = 0;
        for (;;) {
            int a, b, c;
            ld3i(flags + lane, a, b, c);
            int m = wred_min(min(a, min(b, c)));
            if (lane < 32) st_coh_i32(flags + 256 + lane * 16, m);
            if (m >= T_STEPS) break;
            asm volatile("s_sleep 1");
            if ((++it & 63) == 0) {
                if (ld_coh_i32(abp)) break;
                if (it > PVALVE) { if (lane == 0) st_coh_i32(abp, 1); break; }
            }
        }
        return;
    }

    if (tid == 0) lds_ab = 0;

    if (wg < NL0) {
        // ---- layer 0: wave wv owns h0 elem e0 (4 gate rows, K=1024, 64 wt floats/thread) ----
        const int e0 = wg * 16 + wv;
        float w0[4][16], uu[4], vv[4];
#pragma unroll
        for (int g = 0; g < 4; ++g) {
            const int row = g * HDIM + e0;
            const float* pw = Whh0 + (size_t)row * HDIM;
#pragma unroll
            for (int k = 0; k < 16; ++k) w0[g][k] = ld_wreg(pw + lane + 64 * k);
            uu[g] = U[row];
            vv[g] = V[row];
        }
#pragma unroll
        for (int k = 0; k < 8; ++k) ibuf[tid + 1024 * k] = inputs[tid + 1024 * k];
        __syncthreads();

        float c0 = 0.f;
        for (int p = 0; p < T_STEPS; ++p) {
            const int par = p & 1;
            u64 q = 0;
            if (p > 0) {   // predicated poll: thread owns pair tid of h0[p-1] (tag p)
                const u64* src = h0q + (size_t)((p - 1) & RMASK) * 1024 + tid;
                const unsigned xt = (unsigned)p;
                bool need = true;
                long it = 0;
                for (;;) {
                    if (!__ballot(need)) break;
                    if (need) { q = ld_p8(src); need = (ptag(q) != xt); }
                    if ((++it & 255) == 0) {
                        if (ld_coh_i32(abp) || it > PVALVE) {
                            st_coh_i32(abp, 1); lds_ab = 1; break;
                        }
                    }
                }
            }
            kb0[par][tid] = pval(q);
            __syncthreads();
            if (lds_ab) break;
            if ((p & 3) == 3 && tid == 0) st_coh_i32(flags + wg, p + 1);
            float hv[16];
#pragma unroll
            for (int j = 0; j < 16; ++j) hv[j] = kb0[par][lane + 64 * j];
            float acc[4];
#pragma unroll
            for (int g = 0; g < 4; ++g) {
                float s = 0.f;
#pragma unroll
                for (int k = 0; k < 16; ++k) s += w0[g][k] * hv[k];
                acc[g] = s;
            }
#pragma unroll
            for (int g = 0; g < 4; ++g) acc[g] = wred(acc[g]);
            const float st = ibuf[p];
            const float gi = acc[0] + st * uu[0] + vv[0];
            const float gf = acc[1] + st * uu[1] + vv[1];
            const float gg = acc[2] + st * uu[2] + vv[2];
            const float go = acc[3] + st * uu[3] + vv[3];
            const float cn = sigm(gf) * c0 + sigm(gi) * tanhf(gg);
            const float hn = sigm(go) * tanhf(cn);
            c0 = cn;
            if (p >= 48 && (p & 7) == 0 && lane == 0) {   // publisher-lane ring gate
                long itf = 0;
                for (;;) {
                    if (ld_coh_i32(frep) >= p - 40) break;
                    asm volatile("s_sleep 2");
                    if (ld_coh_i32(abp)) break;
                    if (++itf > PVALVE) { st_coh_i32(abp, 1); break; }
                }
            }
            if (lane == 0)
                st_pair(h0q + (size_t)(p & RMASK) * 1024 + e0, pack(hn, p + 1));
        }
        __syncthreads();
        if (tid == 0) st_coh_i32(flags + wg, T_STEPS);
    } else {
        // ---- layer 1: wave-pair owns h1 elem (waves 0-7: Wih1 rows; 8-15: Whh1 rows) ----
        const int wgb = wg - NL0;
        const int half = wv >> 3;
        const int ew = wv & 7;
        const int e = wgb * 8 + ew;
        const float* wsrc = half ? Whh1 : Wih1;
        float w1[4][16];
#pragma unroll
        for (int g = 0; g < 4; ++g) {
            const int row = g * HDIM + e;
            const float* pw = wsrc + (size_t)row * HDIM;
#pragma unroll
            for (int k = 0; k < 16; ++k) w1[g][k] = ld_wreg(pw + lane + 64 * k);
        }
        if (tid < 32) bld[tid] = B1[(tid & 3) * HDIM + wgb * 8 + (tid >> 2)];
        if (tid < 8) wolds[tid] = Wout[wgb * 8 + tid];
        __syncthreads();

        float cst = 0.f;
        for (int t = 0; t < T_STEPS; ++t) {
            const int par = t & 1;
            u64 q0 = 0, q1 = 0;
            {   // predicated dual poll: h0[t] (tag t+1) + h1[t-1] (tag t), pair tid each
                const u64* s0 = h0q + (size_t)(t & RMASK) * 1024 + tid;
                const u64* s1 = h1q + (size_t)((t - 1) & RMASK) * 1024 + tid;
                const unsigned xt0 = (unsigned)(t + 1), xt1 = (unsigned)t;
                bool n0 = true, n1 = (t > 0);
                long it = 0;
                for (;;) {
                    if (!__ballot(n0 | n1)) break;
                    if (n0) { q0 = ld_p8(s0); n0 = (ptag(q0) != xt0); }
                    if (n1) { q1 = ld_p8(s1); n1 = (ptag(q1) != xt1); }
                    if ((++it & 255) == 0) {
                        if (ld_coh_i32(abp) || it > PVALVE) {
                            st_coh_i32(abp, 1); lds_ab = 1; break;
                        }
                    }
                }
            }
            kb0[par][tid] = pval(q0);
            kb1[par][tid] = pval(q1);
            __syncthreads();   // S1
            if (lds_ab) break;
            if (tid == 0) {
                if (t >= 1) part[(size_t)(t - 1) * 128 + wgb] = osum[(t - 1) & 1];
                if ((t & 3) == 3) st_coh_i32(flags + NL0 + wgb, t + 1);
            }
            float hv[16];
            const float* kb = half ? kb1[par] : kb0[par];
#pragma unroll
            for (int j = 0; j < 16; ++j) hv[j] = kb[lane + 64 * j];
            float acc[4];
#pragma unroll
            for (int g = 0; g < 4; ++g) {
                float s = 0.f;
#pragma unroll
                for (int k = 0; k < 16; ++k) s += w1[g][k] * hv[k];
                acc[g] = s;
            }
#pragma unroll
            for (int g = 0; g < 4; ++g) acc[g] = wred(acc[g]);
            if (lane == 0) {
                psum[wv][0] = acc[0]; psum[wv][1] = acc[1];
                psum[wv][2] = acc[2]; psum[wv][3] = acc[3];
            }
            __syncthreads();   // S2
            if (t >= 48 && (t & 7) == 0 && tid == 960) {   // ring gate on wave 15
                long itf = 0;
                for (;;) {
                    if (ld_coh_i32(frep) >= t - 40) break;
                    asm volatile("s_sleep 2");
                    if (ld_coh_i32(abp)) break;
                    if (++itf > PVALVE) { st_coh_i32(abp, 1); break; }
                }
            }
            if (wv == 0) {   // combine + gates + publish for the WG's 8 h1 elems
                float wos = 0.f;
                if (lane < 8) {
                    const float gi = psum[lane][0] + psum[lane + 8][0] + bld[lane * 4 + 0];
                    const float gf = psum[lane][1] + psum[lane + 8][1] + bld[lane * 4 + 1];
                    const float gg = psum[lane][2] + psum[lane + 8][2] + bld[lane * 4 + 2];
                    const float go = psum[lane][3] + psum[lane + 8][3] + bld[lane * 4 + 3];
                    const float cn = sigm(gf) * cst + sigm(gi) * tanhf(gg);
                    const float hn = sigm(go) * tanhf(cn);
                    cst = cn;
                    st_pair(h1q + (size_t)(t & RMASK) * 1024 + wgb * 8 + lane, pack(hn, t + 1));
                    wos = wolds[lane] * hn;
                }
                wos += __shfl_xor(wos, 1, 64);
                wos += __shfl_xor(wos, 2, 64);
                wos += __shfl_xor(wos, 4, 64);
                if (lane == 0) osum[t & 1] = wos;
            }
        }
        __syncthreads();
        if (tid == 0) {
            part[(size_t)(T_STEPS - 1) * 128 + wgb] = osum[(T_STEPS - 1) & 1];
            st_coh_i32(flags + NL0 + wgb, T_STEPS);
        }
    }
}

// ---------- output projection: out[t] = b_out + sum_wb part[t][wb] ----------
__global__ void lstm_finalize(const float* __restrict__ part, const float* __restrict__ bout,
                              float* __restrict__ out) {
    const int t = blockIdx.x * 256 + threadIdx.x;
    if (t < T_STEPS) {
        const float4* p4 = (const float4*)(part + (size_t)t * 128);
        float s = bout[0];
#pragma unroll
        for (int i = 0; i < 32; ++i) {
            float4 v = p4[i];
            s += v.x + v.y + v.z + v.w;
        }
        out[t] = s;
    }
}

extern "C" void kernel_launch(void* const* d_in, const int* in_sizes, int n_in,
                              void* d_out, int out_size, void* d_ws, size_t ws_size,
                              hipStream_t stream) {
    const float* inputs = (const float*)d_in[0];
    const float* Win  = (const float*)d_in[1];
    const float* bin  = (const float*)d_in[2];
    const float* Wih0 = (const float*)d_in[3];
    const float* Whh0 = (const float*)d_in[4];
    const float* bih0 = (const float*)d_in[5];
    const float* bhh0 = (const float*)d_in[6];
    const float* Wih1 = (const float*)d_in[7];
    const float* Whh1 = (const float*)d_in[8];
    const float* bih1 = (const float*)d_in[9];
    const float* bhh1 = (const float*)d_in[10];
    const float* Wout = (const float*)d_in[11];
    const float* bout = (const float*)d_in[12];

    char* ws = (char*)d_ws;
    int*  flags = (int*)ws;                        // 8 KB: progress, floor replicas, abort@1024
    u64*  h0q   = (u64*)(ws + 8192);               // 64*1024*8 = 512 KB
    u64*  h1q   = (u64*)(ws + 8192 + 524288);      // 512 KB (ends 1056768)
    float* U    = (float*)(ws + 1056768);          // 16 KB
    float* V    = (float*)(ws + 1073152);          // 16 KB
    float* B1   = (float*)(ws + 1089536);          // 16 KB (ends 1105920)
    float* part = (float*)(ws + 1105920);          // 8192*128*4 = 4 MB (ends 5300224)

    if (ws_size < (size_t)5300224) return;

    // Rings self-validate via tags (1..8192; 0xAA poison never matches; replay-stale
    // tags carry identical deterministic values). Flags/floor/abort must start at 0.
    hipMemsetAsync(ws, 0, 8192, stream);

    lstm_prologue<<<1024, 256, 0, stream>>>(Wih0, Win, bin, bih0, bhh0, bih1, bhh1, U, V, B1);
    lstm_persistent<<<NWG + 1, 1024, 0, stream>>>(inputs, Whh0, Wih1, Whh1, Wout,
                                                  flags, h0q, h1q, U, V, B1, part);
    lstm_finalize<<<(T_STEPS + 255) / 256, 256, 0, stream>>>(part, bout, (float*)d_out);
}